// Round 3
// baseline (2193.949 us; speedup 1.0000x reference)
//
#include <hip/hip_runtime.h>
#include <hip/hip_fp16.h>
#include <math.h>

// AcousticRadianceTransfer — time-domain + time-sliced XCD-pinned SpMM.
// Identity: rfft multiply by D(d) == circular shift by d + scalar decay.
// The SpMM is time-diagonal (shift applied at store), so the time axis is
// sliced into 25 x 64-sample slices, state stored SLICE-MAJOR, and each
// slice pinned to one XCD (blockIdx%8 round-robin) so each state byte is
// fetched into exactly one L2 per bounce (round-2 counters showed 727 MB
// fetch vs the 614 MB 8-XCD-duplication floor; this targets ~80 MB).
// State bf16, edges packed {fp16 val | uint16 col}, rows degree-sorted.

static constexpr float kSR = 16000.0f;
static constexpr int   kL = 1600;
static constexpr int   kNRad = 24000;
static constexpr int   kNNZ = 480000;
static constexpr int   kNPatch = 256;
static constexpr int   kNBounce = 8;
static constexpr int   kSW = 64;           // samples per slice
static constexpr int   kNS = 25;           // slices (kNS*kSW == kL)
static constexpr int   kRPB = 32;          // rows per block
static constexpr int   kNRB = 750;         // row-blocks (kNRB*kRPB == kNRad)
static constexpr float kLogGamma = -6.907755278982137f; // ln(0.001)

__device__ __forceinline__ unsigned short f2bf(float f) {
    unsigned int u = __float_as_uint(f);
    unsigned int r = u + 0x7fffu + ((u >> 16) & 1u);   // RTN-even
    return (unsigned short)(r >> 16);
}
__device__ __forceinline__ float bflo(unsigned int w) {
    return __uint_as_float(w << 16);
}
__device__ __forceinline__ float bfhi(unsigned int w) {
    return __uint_as_float(w & 0xffff0000u);
}

// ---------------- CSR build + degree sort ----------------

__global__ void k_hist(const int* __restrict__ row, int* __restrict__ cnt) {
    int e = blockIdx.x * 256 + threadIdx.x;
    if (e < kNNZ) atomicAdd(&cnt[row[e]], 1);
}

__global__ void k_deghist(const int* __restrict__ cnt, int* __restrict__ degcnt) {
    int i = blockIdx.x * 256 + threadIdx.x;
    if (i < kNRad) atomicAdd(&degcnt[min(cnt[i], 63)], 1);
}

__global__ void k_degscan(int* __restrict__ degcnt, int* __restrict__ degcur) {
    if (threadIdx.x == 0) {
        int s = 0;
        for (int b = 0; b < 64; ++b) {
            int c = degcnt[b];
            degcnt[b] = s;
            degcur[b] = s;
            s += c;
        }
    }
}

__global__ void k_perm(const int* __restrict__ cnt, int* __restrict__ degcur,
                       int* __restrict__ perm, int* __restrict__ iperm) {
    int i = blockIdx.x * 256 + threadIdx.x;
    if (i >= kNRad) return;
    int b = min(cnt[i], 63);
    int pos = atomicAdd(&degcur[b], 1);
    perm[pos] = i;
    iperm[i] = pos;
}

// exclusive scan of cnt[perm[i]] -> rowptr (sorted-order CSR) + cursor
__global__ void k_scan2(const int* __restrict__ cnt, const int* __restrict__ perm,
                        int* __restrict__ rowptr, int* __restrict__ cursor) {
    __shared__ int s[256];
    __shared__ int carry_s;
    int tid = threadIdx.x;
    if (tid == 0) carry_s = 0;
    __syncthreads();
    for (int base = 0; base < kNRad; base += 256) {
        int i = base + tid;
        int v = (i < kNRad) ? cnt[perm[i]] : 0;
        s[tid] = v;
        __syncthreads();
        for (int off = 1; off < 256; off <<= 1) {
            int t = (tid >= off) ? s[tid - off] : 0;
            __syncthreads();
            s[tid] += t;
            __syncthreads();
        }
        int incl = s[tid];
        int c = carry_s;
        if (i < kNRad) {
            int ex = c + incl - v;
            rowptr[i] = ex;
            cursor[i] = ex;
        }
        __syncthreads();
        if (tid == 255) carry_s = c + incl;
        __syncthreads();
    }
    if (tid == 0) rowptr[kNRad] = carry_s;
}

__global__ void k_scatter(const float* __restrict__ absorb,
                          const float* __restrict__ scat,
                          const float* __restrict__ basis,
                          const int* __restrict__ row,
                          const int* __restrict__ col,
                          const int* __restrict__ rid,
                          const int* __restrict__ iperm,
                          int* __restrict__ cursor,
                          unsigned int* __restrict__ epack) {
    int e = blockIdx.x * 256 + threadIdx.x;
    if (e >= kNNZ) return;
    int rd = rid[e];
    float v = (scat[rd] * basis[e] + scat[kNPatch + rd] * basis[kNNZ + e]) * absorb[rd];
    int p = iperm[row[e]];
    int pos = atomicAdd(&cursor[p], 1);
    unsigned int hv = (unsigned int)__half_as_ushort(__float2half(v));
    epack[pos] = (hv << 16) | (unsigned int)col[e];
}

__global__ void k_decay(const int* __restrict__ delay,
                        float* __restrict__ decay, int* __restrict__ dmod) {
    int i = blockIdx.x * 256 + threadIdx.x;
    if (i >= kNRad) return;
    int d = delay[i];
    decay[i] = expf(kLogGamma * (float)d / kSR);
    dmod[i] = d % kL;
}

// ---------------- init: slice-major bf16 shifted state + ypartA ----------

__global__ __launch_bounds__(256) void k_init(const float* __restrict__ rad,
                                              const float* __restrict__ w,
                                              const float* __restrict__ decay,
                                              const int* __restrict__ dmod,
                                              unsigned short* __restrict__ outS,
                                              float* __restrict__ ypartA) {
    int wg = blockIdx.x, t = threadIdx.x;
    if (t >= 200) return;
    int m0 = 8 * t;
    float fsm[8];
#pragma unroll
    for (int i = 0; i < 8; ++i)
        fsm[i] = expf(kLogGamma * (float)(m0 + i) / kSR);
    float yacc[8] = {0, 0, 0, 0, 0, 0, 0, 0};
    for (int rr = 0; rr < 8; ++rr) {
        int r = wg * 8 + rr;
        const float4* s4 = (const float4*)(rad + (size_t)r * kL);
        float4 a = s4[2 * t], b = s4[2 * t + 1];
        float v[8] = {a.x * fsm[0], a.y * fsm[1], a.z * fsm[2], a.w * fsm[3],
                      b.x * fsm[4], b.y * fsm[5], b.z * fsm[6], b.w * fsm[7]};
        float wr = w[r];
#pragma unroll
        for (int i = 0; i < 8; ++i) yacc[i] = fmaf(wr, v[i], yacc[i]);
        float dec = decay[r];
        int n0 = m0 + dmod[r];
        if (n0 >= kL) n0 -= kL;
#pragma unroll
        for (int i = 0; i < 8; ++i) {
            int n = n0 + i; if (n >= kL) n -= kL;
            outS[((size_t)(n >> 6) * kNRad + r) * kSW + (n & 63)] = f2bf(dec * v[i]);
        }
    }
    float* yp = ypartA + (size_t)wg * kL + m0;
#pragma unroll
    for (int i = 0; i < 8; ++i) yp[i] = yacc[i];
}

// ---------------- one bounce, time-sliced, XCD-pinned ----------------
// grid: bid = ((j*kNRB + rb) << 3) | x ; j<3: slice = x+8j (pinned to XCD x)
// j==3: shared slice 24, only blocks with x == (rb&7) run.

__global__ __launch_bounds__(256) void k_bounce(const unsigned short* __restrict__ inS,
                                                unsigned short* __restrict__ outS,
                                                float* __restrict__ ypart,
                                                const unsigned int* __restrict__ epack,
                                                const int* __restrict__ rowptr,
                                                const int* __restrict__ perm,
                                                const float* __restrict__ w,
                                                const float* __restrict__ decay,
                                                const int* __restrict__ dmod) {
    int bid = blockIdx.x;
    int x = bid & 7;
    int t = bid >> 3;
    int j = t / kNRB;
    int rb = t - j * kNRB;
    int s;
    if (j < 3) {
        s = x + 8 * j;
    } else {
        if (x != (rb & 7)) return;
        s = 24;
    }
    int tid = threadIdx.x;
    int g = tid >> 3;          // row group within block
    int p = tid & 7;           // 16B lane-part within 128B slice-row
    int r = rb * kRPB + g;     // degree-sorted row index
    int o = perm[r];           // original row
    int e0 = rowptr[r], e1 = rowptr[r + 1];
    const unsigned short* sbase = inS + (size_t)s * ((size_t)kNRad * kSW);

    float acc[8] = {0, 0, 0, 0, 0, 0, 0, 0};
    for (int e = e0; e < e1; ++e) {
        unsigned int u = epack[e];
        float v = __half2float(__ushort_as_half((unsigned short)(u >> 16)));
        const uint4* src = (const uint4*)(sbase + (size_t)(u & 0xffffu) * kSW);
        uint4 q = src[p];
        acc[0] = fmaf(v, bflo(q.x), acc[0]);
        acc[1] = fmaf(v, bfhi(q.x), acc[1]);
        acc[2] = fmaf(v, bflo(q.y), acc[2]);
        acc[3] = fmaf(v, bfhi(q.y), acc[3]);
        acc[4] = fmaf(v, bflo(q.z), acc[4]);
        acc[5] = fmaf(v, bfhi(q.z), acc[5]);
        acc[6] = fmaf(v, bflo(q.w), acc[6]);
        acc[7] = fmaf(v, bfhi(q.w), acc[7]);
    }

    // y contribution: reduce w[o]*acc over the 8 row-groups in each wave
    float wr = w[o];
    float y[8];
#pragma unroll
    for (int i = 0; i < 8; ++i) y[i] = wr * acc[i];
#pragma unroll
    for (int m = 8; m <= 32; m <<= 1) {
#pragma unroll
        for (int i = 0; i < 8; ++i) y[i] += __shfl_xor(y[i], m, 64);
    }
    __shared__ float sy[4][64];
    if ((tid & 56) == 0) {
        int wv = tid >> 6;
#pragma unroll
        for (int i = 0; i < 8; ++i) sy[wv][p * 8 + i] = y[i];
    }
    __syncthreads();
    if (tid < 64) {
        float t4 = sy[0][tid] + sy[1][tid] + sy[2][tid] + sy[3][tid];
        ypart[(size_t)rb * kL + s * kSW + tid] += t4;
    }

    // shifted + decayed bf16 store into slice-major next-state
    float dec = decay[o];
    int n0 = s * kSW + p * 8 + dmod[o];
    if (n0 >= kL) n0 -= kL;
#pragma unroll
    for (int i = 0; i < 8; ++i) {
        int n = n0 + i; if (n >= kL) n -= kL;
        outS[((size_t)(n >> 6) * kNRad + o) * kSW + (n & 63)] = f2bf(dec * acc[i]);
    }
}

// ---------------- finish ----------------

__global__ void k_finish(const float* __restrict__ ypA,
                         const float* __restrict__ ypB,
                         const float* __restrict__ env,
                         float* __restrict__ out) {
    int n = blockIdx.x * 256 + threadIdx.x;
    if (n >= kL) return;
    float s = 0.0f;
    for (int i = 0; i < 3000; ++i) s += ypA[(size_t)i * kL + n];
    for (int i = 0; i < kNRB; ++i) s += ypB[(size_t)i * kL + n];
    float t = (float)n / kSR;
    out[n] = s * expf(env[n] - kLogGamma * t);
}

extern "C" void kernel_launch(void* const* d_in, const int* in_sizes, int n_in,
                              void* d_out, int out_size, void* d_ws, size_t ws_size,
                              hipStream_t stream) {
    const float* absorb = (const float*)d_in[0];
    const float* scat   = (const float*)d_in[1];
    const float* rad    = (const float*)d_in[2];
    const float* w      = (const float*)d_in[3];
    const float* env    = (const float*)d_in[4];
    const float* basis  = (const float*)d_in[5];
    const int*   srow   = (const int*)d_in[6];
    const int*   scol   = (const int*)d_in[7];
    const int*   srid   = (const int*)d_in[8];
    const int*   delay  = (const int*)d_in[9];

    char* ws = (char*)d_ws;
    size_t off = 0;
    auto alloc = [&](size_t bytes) -> char* {
        char* p = ws + off;
        off += (bytes + 255) & ~size_t(255);
        return p;
    };
    unsigned short* curA = (unsigned short*)alloc((size_t)kNS * kNRad * kSW * 2);
    unsigned short* curB = (unsigned short*)alloc((size_t)kNS * kNRad * kSW * 2);
    float* ypartA = (float*)alloc((size_t)3000 * kL * 4);
    float* ypartB = (float*)alloc((size_t)kNRB * kL * 4);
    unsigned int* epack = (unsigned int*)alloc((size_t)kNNZ * 4);
    int*   rowptr = (int*)alloc((size_t)(kNRad + 1) * 4);
    int*   cursor = (int*)alloc((size_t)kNRad * 4);
    int*   cnt    = (int*)alloc((size_t)kNRad * 4);
    int*   perm   = (int*)alloc((size_t)kNRad * 4);
    int*   iperm  = (int*)alloc((size_t)kNRad * 4);
    float* decay  = (float*)alloc((size_t)kNRad * 4);
    int*   dmod   = (int*)alloc((size_t)kNRad * 4);
    int*   degcnt = (int*)alloc(64 * 4);
    int*   degcur = (int*)alloc(64 * 4);
    (void)ws_size; (void)in_sizes; (void)n_in; (void)out_size;

    hipMemsetAsync(cnt, 0, (size_t)kNRad * 4, stream);
    hipMemsetAsync(degcnt, 0, 64 * 4, stream);
    hipMemsetAsync(ypartB, 0, (size_t)kNRB * kL * 4, stream);

    k_hist<<<(kNNZ + 255) / 256, 256, 0, stream>>>(srow, cnt);
    k_deghist<<<(kNRad + 255) / 256, 256, 0, stream>>>(cnt, degcnt);
    k_degscan<<<1, 64, 0, stream>>>(degcnt, degcur);
    k_perm<<<(kNRad + 255) / 256, 256, 0, stream>>>(cnt, degcur, perm, iperm);
    k_scan2<<<1, 256, 0, stream>>>(cnt, perm, rowptr, cursor);
    k_decay<<<(kNRad + 255) / 256, 256, 0, stream>>>(delay, decay, dmod);
    k_scatter<<<(kNNZ + 255) / 256, 256, 0, stream>>>(absorb, scat, basis, srow,
                                                      scol, srid, iperm, cursor, epack);

    k_init<<<3000, 256, 0, stream>>>(rad, w, decay, dmod, curA, ypartA);

    const unsigned short* in = curA;
    unsigned short* outb = curB;
    for (int b = 0; b < kNBounce; ++b) {
        k_bounce<<<4 * kNRB * 8, 256, 0, stream>>>(in, outb, ypartB, epack, rowptr,
                                                   perm, w, decay, dmod);
        const unsigned short* tmp = outb;
        outb = (unsigned short*)in;
        in = tmp;
    }

    k_finish<<<(kL + 255) / 256, 256, 0, stream>>>(ypartA, ypartB, env, (float*)d_out);
}

// Round 4
// 1946.478 us; speedup vs baseline: 1.1271x; 1.1271x over previous
//
#include <hip/hip_runtime.h>
#include <hip/hip_fp16.h>
#include <math.h>

// AcousticRadianceTransfer — time-domain, time-sliced, XCD-pinned SpMM, v4.
// Round-3 lesson: bottleneck is VMEM issue (TA) on the shifted-store scatter
// (2B x stride-16B lanes = ~12 lines per store instr), not cache-miss bytes.
// v4: (a) stores made lane-contiguous via in-wave LDS transpose (one wave-wide
// row store = 1-3 lines), (b) each block processes all 3-4 slices its XCD
// owns (amortizes edge loads 3.25x, 3-4 gathers in flight per iteration),
// (c) slice-24 tail folded into owner blocks, (d) k_init restructured the
// same way, (e) two-stage finish reduction.

static constexpr float kSR = 16000.0f;
static constexpr int   kL = 1600;
static constexpr int   kNRad = 24000;
static constexpr int   kNNZ = 480000;
static constexpr int   kNPatch = 256;
static constexpr int   kNBounce = 8;
static constexpr int   kSW = 64;           // samples per slice
static constexpr int   kNS = 25;           // slices
static constexpr int   kNRB = 750;         // row-blocks of 32 rows
static constexpr float kLogGamma = -6.907755278982137f; // ln(0.001)

__device__ __forceinline__ unsigned short f2bf(float f) {
    unsigned int u = __float_as_uint(f);
    unsigned int r = u + 0x7fffu + ((u >> 16) & 1u);   // RTN-even
    return (unsigned short)(r >> 16);
}
__device__ __forceinline__ float bflo(unsigned int w) {
    return __uint_as_float(w << 16);
}
__device__ __forceinline__ float bfhi(unsigned int w) {
    return __uint_as_float(w & 0xffff0000u);
}
__device__ __forceinline__ void fma8(float (&a)[8], float v, const uint4 q) {
    a[0] = fmaf(v, bflo(q.x), a[0]);
    a[1] = fmaf(v, bfhi(q.x), a[1]);
    a[2] = fmaf(v, bflo(q.y), a[2]);
    a[3] = fmaf(v, bfhi(q.y), a[3]);
    a[4] = fmaf(v, bflo(q.z), a[4]);
    a[5] = fmaf(v, bfhi(q.z), a[5]);
    a[6] = fmaf(v, bflo(q.w), a[6]);
    a[7] = fmaf(v, bfhi(q.w), a[7]);
}

// ---------------- CSR build + degree sort (unchanged from r3) ----------------

__global__ void k_hist(const int* __restrict__ row, int* __restrict__ cnt) {
    int e = blockIdx.x * 256 + threadIdx.x;
    if (e < kNNZ) atomicAdd(&cnt[row[e]], 1);
}

__global__ void k_deghist(const int* __restrict__ cnt, int* __restrict__ degcnt) {
    int i = blockIdx.x * 256 + threadIdx.x;
    if (i < kNRad) atomicAdd(&degcnt[min(cnt[i], 63)], 1);
}

__global__ void k_degscan(int* __restrict__ degcnt, int* __restrict__ degcur) {
    if (threadIdx.x == 0) {
        int s = 0;
        for (int b = 0; b < 64; ++b) {
            int c = degcnt[b];
            degcnt[b] = s;
            degcur[b] = s;
            s += c;
        }
    }
}

__global__ void k_perm(const int* __restrict__ cnt, int* __restrict__ degcur,
                       int* __restrict__ perm, int* __restrict__ iperm) {
    int i = blockIdx.x * 256 + threadIdx.x;
    if (i >= kNRad) return;
    int b = min(cnt[i], 63);
    int pos = atomicAdd(&degcur[b], 1);
    perm[pos] = i;
    iperm[i] = pos;
}

__global__ void k_scan2(const int* __restrict__ cnt, const int* __restrict__ perm,
                        int* __restrict__ rowptr, int* __restrict__ cursor) {
    __shared__ int s[256];
    __shared__ int carry_s;
    int tid = threadIdx.x;
    if (tid == 0) carry_s = 0;
    __syncthreads();
    for (int base = 0; base < kNRad; base += 256) {
        int i = base + tid;
        int v = (i < kNRad) ? cnt[perm[i]] : 0;
        s[tid] = v;
        __syncthreads();
        for (int off = 1; off < 256; off <<= 1) {
            int t = (tid >= off) ? s[tid - off] : 0;
            __syncthreads();
            s[tid] += t;
            __syncthreads();
        }
        int incl = s[tid];
        int c = carry_s;
        if (i < kNRad) {
            int ex = c + incl - v;
            rowptr[i] = ex;
            cursor[i] = ex;
        }
        __syncthreads();
        if (tid == 255) carry_s = c + incl;
        __syncthreads();
    }
    if (tid == 0) rowptr[kNRad] = carry_s;
}

__global__ void k_scatter(const float* __restrict__ absorb,
                          const float* __restrict__ scat,
                          const float* __restrict__ basis,
                          const int* __restrict__ row,
                          const int* __restrict__ col,
                          const int* __restrict__ rid,
                          const int* __restrict__ iperm,
                          int* __restrict__ cursor,
                          unsigned int* __restrict__ epack) {
    int e = blockIdx.x * 256 + threadIdx.x;
    if (e >= kNNZ) return;
    int rd = rid[e];
    float v = (scat[rd] * basis[e] + scat[kNPatch + rd] * basis[kNNZ + e]) * absorb[rd];
    int p = iperm[row[e]];
    int pos = atomicAdd(&cursor[p], 1);
    unsigned int hv = (unsigned int)__half_as_ushort(__float2half(v));
    epack[pos] = (hv << 16) | (unsigned int)col[e];
}

__global__ void k_decay(const int* __restrict__ delay,
                        float* __restrict__ decay, int* __restrict__ dmod) {
    int i = blockIdx.x * 256 + threadIdx.x;
    if (i >= kNRad) return;
    int d = delay[i];
    decay[i] = expf(kLogGamma * (float)d / kSR);
    dmod[i] = d % kL;
}

// ---------------- init: slice-major bf16 shifted state + ypartA --------------
// wave = 8 rows; k-loop over 25 slices; lane l <-> sample 64k+l.
// Stores are lane-contiguous (circular run of 64 samples, 1-3 lines).

__global__ __launch_bounds__(256) void k_init(const float* __restrict__ rad,
                                              const float* __restrict__ w,
                                              const float* __restrict__ decay,
                                              const int* __restrict__ dmod,
                                              unsigned short* __restrict__ outS,
                                              float* __restrict__ ypartA) {
    int rb = blockIdx.x;
    int tid = threadIdx.x, wv = tid >> 6, lane = tid & 63;
    const size_t SS = (size_t)kNRad * kSW;
    for (int k = 0; k < kNS; ++k) {
        int m = k * kSW + lane;
        float fs = expf(kLogGamma * (float)m / kSR);
        float y = 0.0f;
#pragma unroll
        for (int g = 0; g < 8; ++g) {
            int r = rb * 32 + wv * 8 + g;
            float v = rad[(size_t)r * kL + m] * fs;
            y = fmaf(w[r], v, y);
            int n = m + dmod[r];
            if (n >= kL) n -= kL;
            outS[(size_t)(n >> 6) * SS + (size_t)r * kSW + (n & 63)] =
                f2bf(decay[r] * v);
        }
        ypartA[((size_t)(rb * 4 + wv)) * kL + m] = y;
    }
}

// ---------------- one bounce: block (rb, x) does slices {x, x+8, x+16} -------
// (+ slice 24 if x == rb&7). Edge loop once per block; 3-4 gathers per edge.
// Store via in-wave LDS transpose -> wave-wide contiguous row store.

__global__ __launch_bounds__(256) void k_bounce(const unsigned short* __restrict__ inS,
                                                unsigned short* __restrict__ outS,
                                                float* __restrict__ ypart,
                                                const unsigned int* __restrict__ epack,
                                                const int* __restrict__ rowptr,
                                                const int* __restrict__ perm,
                                                const float* __restrict__ w,
                                                const float* __restrict__ decay,
                                                const int* __restrict__ dmod) {
    int bid = blockIdx.x;
    int x = bid & 7;
    int rb = bid >> 3;
    int tid = threadIdx.x, wv = tid >> 6, lane = tid & 63;
    int g = lane >> 3, p = lane & 7;
    int r = rb * 32 + wv * 8 + g;
    int e0 = rowptr[r], e1 = rowptr[r + 1];
    bool own24 = ((rb & 7) == x);
    const size_t SS = (size_t)kNRad * kSW;      // shorts per slice
    const unsigned short* b0 = inS + (size_t)x * SS + (size_t)p * 8;
    const unsigned short* b3 = inS + (size_t)24 * SS + (size_t)p * 8;

    float acc0[8] = {0, 0, 0, 0, 0, 0, 0, 0};
    float acc1[8] = {0, 0, 0, 0, 0, 0, 0, 0};
    float acc2[8] = {0, 0, 0, 0, 0, 0, 0, 0};
    float acc3[8] = {0, 0, 0, 0, 0, 0, 0, 0};

    for (int e = e0; e < e1; ++e) {
        unsigned int u = epack[e];
        float v = __half2float(__ushort_as_half((unsigned short)(u >> 16)));
        size_t co = (size_t)(u & 0xffffu) * kSW;   // shorts
        uint4 q0 = *(const uint4*)(b0 + co);
        uint4 q1 = *(const uint4*)(b0 + 8 * SS + co);
        uint4 q2 = *(const uint4*)(b0 + 16 * SS + co);
        fma8(acc0, v, q0);
        fma8(acc1, v, q1);
        fma8(acc2, v, q2);
        if (own24) {
            uint4 q3 = *(const uint4*)(b3 + co);
            fma8(acc3, v, q3);
        }
    }

    __shared__ float tb[4][8][64];
    float* ypB = ypart + ((size_t)(rb * 4 + wv)) * kL;

    auto emit = [&](const float (&A)[8], int S) {
#pragma unroll
        for (int i = 0; i < 8; ++i) tb[wv][g][p * 8 + i] = A[i];
        float yk = 0.0f;
#pragma unroll
        for (int g2 = 0; g2 < 8; ++g2) {
            int o2 = perm[rb * 32 + wv * 8 + g2];
            float val = tb[wv][g2][lane];
            yk = fmaf(w[o2], val, yk);
            int n = S * kSW + lane + dmod[o2];
            if (n >= kL) n -= kL;
            if (n >= kL) n -= kL;
            outS[(size_t)(n >> 6) * SS + (size_t)o2 * kSW + (n & 63)] =
                f2bf(decay[o2] * val);
        }
        ypB[S * kSW + lane] += yk;
    };

    emit(acc0, x);
    emit(acc1, x + 8);
    emit(acc2, x + 16);
    if (own24) emit(acc3, 24);
}

// ---------------- finish: two-stage reduction ----------------

__global__ void k_red1(const float* __restrict__ ypA,
                       const float* __restrict__ ypB,
                       float* __restrict__ partial) {
    int c = blockIdx.x / 7;       // 24 chunks
    int nb = blockIdx.x % 7;
    int n = nb * 256 + threadIdx.x;
    if (n >= kL) return;
    float s = 0.0f;
    int r0 = c * 125;
    for (int i = 0; i < 125; ++i) s += ypA[(size_t)(r0 + i) * kL + n];
    for (int i = 0; i < 125; ++i) s += ypB[(size_t)(r0 + i) * kL + n];
    partial[(size_t)c * kL + n] = s;
}

__global__ void k_red2(const float* __restrict__ partial,
                       const float* __restrict__ env,
                       float* __restrict__ out) {
    int n = blockIdx.x * 256 + threadIdx.x;
    if (n >= kL) return;
    float s = 0.0f;
#pragma unroll
    for (int c = 0; c < 24; ++c) s += partial[(size_t)c * kL + n];
    float t = (float)n / kSR;
    out[n] = s * expf(env[n] - kLogGamma * t);
}

extern "C" void kernel_launch(void* const* d_in, const int* in_sizes, int n_in,
                              void* d_out, int out_size, void* d_ws, size_t ws_size,
                              hipStream_t stream) {
    const float* absorb = (const float*)d_in[0];
    const float* scat   = (const float*)d_in[1];
    const float* rad    = (const float*)d_in[2];
    const float* w      = (const float*)d_in[3];
    const float* env    = (const float*)d_in[4];
    const float* basis  = (const float*)d_in[5];
    const int*   srow   = (const int*)d_in[6];
    const int*   scol   = (const int*)d_in[7];
    const int*   srid   = (const int*)d_in[8];
    const int*   delay  = (const int*)d_in[9];

    char* ws = (char*)d_ws;
    size_t off = 0;
    auto alloc = [&](size_t bytes) -> char* {
        char* p = ws + off;
        off += (bytes + 255) & ~size_t(255);
        return p;
    };
    unsigned short* curA = (unsigned short*)alloc((size_t)kNS * kNRad * kSW * 2);
    unsigned short* curB = (unsigned short*)alloc((size_t)kNS * kNRad * kSW * 2);
    float* ypartA = (float*)alloc((size_t)3000 * kL * 4);
    float* ypartB = (float*)alloc((size_t)3000 * kL * 4);
    float* partial = (float*)alloc((size_t)24 * kL * 4);
    unsigned int* epack = (unsigned int*)alloc((size_t)kNNZ * 4);
    int*   rowptr = (int*)alloc((size_t)(kNRad + 1) * 4);
    int*   cursor = (int*)alloc((size_t)kNRad * 4);
    int*   cnt    = (int*)alloc((size_t)kNRad * 4);
    int*   perm   = (int*)alloc((size_t)kNRad * 4);
    int*   iperm  = (int*)alloc((size_t)kNRad * 4);
    float* decay  = (float*)alloc((size_t)kNRad * 4);
    int*   dmod   = (int*)alloc((size_t)kNRad * 4);
    int*   degcnt = (int*)alloc(64 * 4);
    int*   degcur = (int*)alloc(64 * 4);
    (void)ws_size; (void)in_sizes; (void)n_in; (void)out_size;

    hipMemsetAsync(cnt, 0, (size_t)kNRad * 4, stream);
    hipMemsetAsync(degcnt, 0, 64 * 4, stream);
    hipMemsetAsync(ypartB, 0, (size_t)3000 * kL * 4, stream);

    k_hist<<<(kNNZ + 255) / 256, 256, 0, stream>>>(srow, cnt);
    k_deghist<<<(kNRad + 255) / 256, 256, 0, stream>>>(cnt, degcnt);
    k_degscan<<<1, 64, 0, stream>>>(degcnt, degcur);
    k_perm<<<(kNRad + 255) / 256, 256, 0, stream>>>(cnt, degcur, perm, iperm);
    k_scan2<<<1, 256, 0, stream>>>(cnt, perm, rowptr, cursor);
    k_decay<<<(kNRad + 255) / 256, 256, 0, stream>>>(delay, decay, dmod);
    k_scatter<<<(kNNZ + 255) / 256, 256, 0, stream>>>(absorb, scat, basis, srow,
                                                      scol, srid, iperm, cursor, epack);

    k_init<<<kNRB, 256, 0, stream>>>(rad, w, decay, dmod, curA, ypartA);

    const unsigned short* in = curA;
    unsigned short* outb = curB;
    for (int b = 0; b < kNBounce; ++b) {
        k_bounce<<<kNRB * 8, 256, 0, stream>>>(in, outb, ypartB, epack, rowptr,
                                               perm, w, decay, dmod);
        const unsigned short* tmp = outb;
        outb = (unsigned short*)in;
        in = tmp;
    }

    k_red1<<<24 * 7, 256, 0, stream>>>(ypartA, ypartB, partial);
    k_red2<<<(kL + 255) / 256, 256, 0, stream>>>(partial, env, (float*)d_out);
}

// Round 5
// 1645.935 us; speedup vs baseline: 1.3330x; 1.1826x over previous
//
#include <hip/hip_runtime.h>
#include <hip/hip_fp16.h>
#include <math.h>

// AcousticRadianceTransfer — time-domain, time-sliced, XCD-pinned SpMM, v5.
// Round 2-4 lesson: runtime is pinned by gather-miss throughput =
// (waves x in-flight gathers) / latency, NOT by bytes. v5 maximizes MLP
// (edge loop unrolled x4, 4 independent uint4 gathers in flight) while
// restoring L2-hit latency (phase-major grid: one 3.07MB slice per XCD at a
// time) and occupancy (single acc[8], ~50 VGPR). Stores stay LDS-transposed
// wave-contiguous. State bf16, edges {fp16 val | u16 col}, degree-sorted.

static constexpr float kSR = 16000.0f;
static constexpr int   kL = 1600;
static constexpr int   kNRad = 24000;
static constexpr int   kNNZ = 480000;
static constexpr int   kNPatch = 256;
static constexpr int   kNBounce = 8;
static constexpr int   kSW = 64;           // samples per slice
static constexpr int   kNS = 25;           // slices
static constexpr int   kNRB = 750;         // row-blocks of 32 rows
static constexpr float kLogGamma = -6.907755278982137f; // ln(0.001)

__device__ __forceinline__ unsigned short f2bf(float f) {
    unsigned int u = __float_as_uint(f);
    unsigned int r = u + 0x7fffu + ((u >> 16) & 1u);   // RTN-even
    return (unsigned short)(r >> 16);
}
__device__ __forceinline__ float bflo(unsigned int w) {
    return __uint_as_float(w << 16);
}
__device__ __forceinline__ float bfhi(unsigned int w) {
    return __uint_as_float(w & 0xffff0000u);
}
__device__ __forceinline__ float h2f(unsigned int hv) {
    return __half2float(__ushort_as_half((unsigned short)hv));
}
__device__ __forceinline__ void fma8(float (&a)[8], float v, const uint4 q) {
    a[0] = fmaf(v, bflo(q.x), a[0]);
    a[1] = fmaf(v, bfhi(q.x), a[1]);
    a[2] = fmaf(v, bflo(q.y), a[2]);
    a[3] = fmaf(v, bfhi(q.y), a[3]);
    a[4] = fmaf(v, bflo(q.z), a[4]);
    a[5] = fmaf(v, bfhi(q.z), a[5]);
    a[6] = fmaf(v, bflo(q.w), a[6]);
    a[7] = fmaf(v, bfhi(q.w), a[7]);
}

// ---------------- CSR build + degree sort ----------------

__global__ void k_hist(const int* __restrict__ row, int* __restrict__ cnt) {
    int e = blockIdx.x * 256 + threadIdx.x;
    if (e < kNNZ) atomicAdd(&cnt[row[e]], 1);
}

__global__ void k_deghist(const int* __restrict__ cnt, int* __restrict__ degcnt) {
    int i = blockIdx.x * 256 + threadIdx.x;
    if (i < kNRad) atomicAdd(&degcnt[min(cnt[i], 63)], 1);
}

__global__ void k_degscan(int* __restrict__ degcnt, int* __restrict__ degcur) {
    if (threadIdx.x == 0) {
        int s = 0;
        for (int b = 0; b < 64; ++b) {
            int c = degcnt[b];
            degcnt[b] = s;
            degcur[b] = s;
            s += c;
        }
    }
}

__global__ void k_perm(const int* __restrict__ cnt, int* __restrict__ degcur,
                       int* __restrict__ perm, int* __restrict__ iperm) {
    int i = blockIdx.x * 256 + threadIdx.x;
    if (i >= kNRad) return;
    int b = min(cnt[i], 63);
    int pos = atomicAdd(&degcur[b], 1);
    perm[pos] = i;
    iperm[i] = pos;
}

__global__ void k_scan2(const int* __restrict__ cnt, const int* __restrict__ perm,
                        int* __restrict__ rowptr, int* __restrict__ cursor) {
    __shared__ int s[256];
    __shared__ int carry_s;
    int tid = threadIdx.x;
    if (tid == 0) carry_s = 0;
    __syncthreads();
    for (int base = 0; base < kNRad; base += 256) {
        int i = base + tid;
        int v = (i < kNRad) ? cnt[perm[i]] : 0;
        s[tid] = v;
        __syncthreads();
        for (int off = 1; off < 256; off <<= 1) {
            int t = (tid >= off) ? s[tid - off] : 0;
            __syncthreads();
            s[tid] += t;
            __syncthreads();
        }
        int incl = s[tid];
        int c = carry_s;
        if (i < kNRad) {
            int ex = c + incl - v;
            rowptr[i] = ex;
            cursor[i] = ex;
        }
        __syncthreads();
        if (tid == 255) carry_s = c + incl;
        __syncthreads();
    }
    if (tid == 0) rowptr[kNRad] = carry_s;
}

__global__ void k_scatter(const float* __restrict__ absorb,
                          const float* __restrict__ scat,
                          const float* __restrict__ basis,
                          const int* __restrict__ row,
                          const int* __restrict__ col,
                          const int* __restrict__ rid,
                          const int* __restrict__ iperm,
                          int* __restrict__ cursor,
                          unsigned int* __restrict__ epack) {
    int e = blockIdx.x * 256 + threadIdx.x;
    if (e >= kNNZ) return;
    int rd = rid[e];
    float v = (scat[rd] * basis[e] + scat[kNPatch + rd] * basis[kNNZ + e]) * absorb[rd];
    int p = iperm[row[e]];
    int pos = atomicAdd(&cursor[p], 1);
    unsigned int hv = (unsigned int)__half_as_ushort(__float2half(v));
    epack[pos] = (hv << 16) | (unsigned int)col[e];
}

__global__ void k_decay(const int* __restrict__ delay,
                        float* __restrict__ decay, int* __restrict__ dmod) {
    int i = blockIdx.x * 256 + threadIdx.x;
    if (i >= kNRad) return;
    int d = delay[i];
    decay[i] = expf(kLogGamma * (float)d / kSR);
    dmod[i] = d % kL;
}

// ---------------- init: slice-major bf16 shifted state + ypartA --------------
// 3000 blocks x 1 wave; 8 rows per block; lane <-> sample-in-slice.

__global__ __launch_bounds__(64) void k_init(const float* __restrict__ rad,
                                             const float* __restrict__ w,
                                             const float* __restrict__ decay,
                                             const int* __restrict__ dmod,
                                             unsigned short* __restrict__ outS,
                                             float* __restrict__ ypartA) {
    int bid = blockIdx.x;
    int lane = threadIdx.x;
    const size_t SS = (size_t)kNRad * kSW;
    for (int k = 0; k < kNS; ++k) {
        int m = k * kSW + lane;
        float fs = expf(kLogGamma * (float)m / kSR);
        float y = 0.0f;
#pragma unroll
        for (int g = 0; g < 8; ++g) {
            int r = bid * 8 + g;
            float v = rad[(size_t)r * kL + m] * fs;
            y = fmaf(w[r], v, y);
            int n = m + dmod[r];
            if (n >= kL) n -= kL;
            outS[(size_t)(n >> 6) * SS + (size_t)r * kSW + (n & 63)] =
                f2bf(decay[r] * v);
        }
        ypartA[(size_t)bid * kL + m] = y;
    }
}

// ---------------- one bounce, phase-major, MLP-4 edge loop ----------------
// bid = (phase*kNRB + rb)*8 + x ; slice S = x + 8*phase (phase 0..2).
// Phase-2 blocks with rb&7==x also do slice 24 afterwards.

__global__ __launch_bounds__(256) void k_bounce(const unsigned short* __restrict__ inS,
                                                unsigned short* __restrict__ outS,
                                                float* __restrict__ ypart,
                                                const unsigned int* __restrict__ epack,
                                                const int* __restrict__ rowptr,
                                                const int* __restrict__ perm,
                                                const float* __restrict__ w,
                                                const float* __restrict__ decay,
                                                const int* __restrict__ dmod) {
    int bid = blockIdx.x;
    int x = bid & 7;
    int t = bid >> 3;
    int phase = t / kNRB;
    int rb = t - phase * kNRB;
    int tid = threadIdx.x, wv = tid >> 6, lane = tid & 63;
    int g = lane >> 3, p = lane & 7;
    int r = rb * 32 + wv * 8 + g;
    int e0 = rowptr[r], e1 = rowptr[r + 1];
    const size_t SS = (size_t)kNRad * kSW;
    __shared__ float tb[4][8][64];

    auto do_slice = [&](int S) {
        const unsigned short* b = inS + (size_t)S * SS + (size_t)p * 8;
        float acc[8] = {0, 0, 0, 0, 0, 0, 0, 0};
        int e = e0;
        for (; e + 4 <= e1; e += 4) {
            unsigned int u0 = epack[e];
            unsigned int u1 = epack[e + 1];
            unsigned int u2 = epack[e + 2];
            unsigned int u3 = epack[e + 3];
            uint4 q0 = *(const uint4*)(b + (size_t)(u0 & 0xffffu) * kSW);
            uint4 q1 = *(const uint4*)(b + (size_t)(u1 & 0xffffu) * kSW);
            uint4 q2 = *(const uint4*)(b + (size_t)(u2 & 0xffffu) * kSW);
            uint4 q3 = *(const uint4*)(b + (size_t)(u3 & 0xffffu) * kSW);
            fma8(acc, h2f(u0 >> 16), q0);
            fma8(acc, h2f(u1 >> 16), q1);
            fma8(acc, h2f(u2 >> 16), q2);
            fma8(acc, h2f(u3 >> 16), q3);
        }
        for (; e < e1; ++e) {
            unsigned int u = epack[e];
            uint4 q = *(const uint4*)(b + (size_t)(u & 0xffffu) * kSW);
            fma8(acc, h2f(u >> 16), q);
        }
        // LDS transpose -> wave-contiguous shifted+decayed stores + y reduce
#pragma unroll
        for (int i = 0; i < 8; ++i) tb[wv][g][p * 8 + i] = acc[i];
        float yk = 0.0f;
#pragma unroll
        for (int g2 = 0; g2 < 8; ++g2) {
            int o2 = perm[rb * 32 + wv * 8 + g2];
            float val = tb[wv][g2][lane];
            yk = fmaf(w[o2], val, yk);
            int n = S * kSW + lane + dmod[o2];
            if (n >= kL) n -= kL;
            if (n >= kL) n -= kL;
            outS[(size_t)(n >> 6) * SS + (size_t)o2 * kSW + (n & 63)] =
                f2bf(decay[o2] * val);
        }
        ypart[((size_t)(rb * 4 + wv)) * kL + S * kSW + lane] += yk;
    };

    do_slice(x + 8 * phase);
    if (phase == 2 && ((rb & 7) == x)) do_slice(24);
}

// ---------------- finish: two-stage reduction ----------------

__global__ void k_red1(const float* __restrict__ ypA,
                       const float* __restrict__ ypB,
                       float* __restrict__ partial) {
    int c = blockIdx.x / 7;       // 24 chunks
    int nb = blockIdx.x % 7;
    int n = nb * 256 + threadIdx.x;
    if (n >= kL) return;
    float s = 0.0f;
    int r0 = c * 125;
    for (int i = 0; i < 125; ++i) s += ypA[(size_t)(r0 + i) * kL + n];
    for (int i = 0; i < 125; ++i) s += ypB[(size_t)(r0 + i) * kL + n];
    partial[(size_t)c * kL + n] = s;
}

__global__ void k_red2(const float* __restrict__ partial,
                       const float* __restrict__ env,
                       float* __restrict__ out) {
    int n = blockIdx.x * 256 + threadIdx.x;
    if (n >= kL) return;
    float s = 0.0f;
#pragma unroll
    for (int c = 0; c < 24; ++c) s += partial[(size_t)c * kL + n];
    float t = (float)n / kSR;
    out[n] = s * expf(env[n] - kLogGamma * t);
}

extern "C" void kernel_launch(void* const* d_in, const int* in_sizes, int n_in,
                              void* d_out, int out_size, void* d_ws, size_t ws_size,
                              hipStream_t stream) {
    const float* absorb = (const float*)d_in[0];
    const float* scat   = (const float*)d_in[1];
    const float* rad    = (const float*)d_in[2];
    const float* w      = (const float*)d_in[3];
    const float* env    = (const float*)d_in[4];
    const float* basis  = (const float*)d_in[5];
    const int*   srow   = (const int*)d_in[6];
    const int*   scol   = (const int*)d_in[7];
    const int*   srid   = (const int*)d_in[8];
    const int*   delay  = (const int*)d_in[9];

    char* ws = (char*)d_ws;
    size_t off = 0;
    auto alloc = [&](size_t bytes) -> char* {
        char* p = ws + off;
        off += (bytes + 255) & ~size_t(255);
        return p;
    };
    unsigned short* curA = (unsigned short*)alloc((size_t)kNS * kNRad * kSW * 2);
    unsigned short* curB = (unsigned short*)alloc((size_t)kNS * kNRad * kSW * 2);
    float* ypartA = (float*)alloc((size_t)3000 * kL * 4);
    float* ypartB = (float*)alloc((size_t)3000 * kL * 4);
    float* partial = (float*)alloc((size_t)24 * kL * 4);
    unsigned int* epack = (unsigned int*)alloc((size_t)kNNZ * 4);
    int*   rowptr = (int*)alloc((size_t)(kNRad + 1) * 4);
    int*   cursor = (int*)alloc((size_t)kNRad * 4);
    int*   cnt    = (int*)alloc((size_t)kNRad * 4);
    int*   perm   = (int*)alloc((size_t)kNRad * 4);
    int*   iperm  = (int*)alloc((size_t)kNRad * 4);
    float* decay  = (float*)alloc((size_t)kNRad * 4);
    int*   dmod   = (int*)alloc((size_t)kNRad * 4);
    int*   degcnt = (int*)alloc(64 * 4);
    int*   degcur = (int*)alloc(64 * 4);
    (void)ws_size; (void)in_sizes; (void)n_in; (void)out_size;

    hipMemsetAsync(cnt, 0, (size_t)kNRad * 4, stream);
    hipMemsetAsync(degcnt, 0, 64 * 4, stream);
    hipMemsetAsync(ypartB, 0, (size_t)3000 * kL * 4, stream);

    k_hist<<<(kNNZ + 255) / 256, 256, 0, stream>>>(srow, cnt);
    k_deghist<<<(kNRad + 255) / 256, 256, 0, stream>>>(cnt, degcnt);
    k_degscan<<<1, 64, 0, stream>>>(degcnt, degcur);
    k_perm<<<(kNRad + 255) / 256, 256, 0, stream>>>(cnt, degcur, perm, iperm);
    k_scan2<<<1, 256, 0, stream>>>(cnt, perm, rowptr, cursor);
    k_decay<<<(kNRad + 255) / 256, 256, 0, stream>>>(delay, decay, dmod);
    k_scatter<<<(kNNZ + 255) / 256, 256, 0, stream>>>(absorb, scat, basis, srow,
                                                      scol, srid, iperm, cursor, epack);

    k_init<<<3000, 64, 0, stream>>>(rad, w, decay, dmod, curA, ypartA);

    const unsigned short* in = curA;
    unsigned short* outb = curB;
    for (int b = 0; b < kNBounce; ++b) {
        k_bounce<<<3 * kNRB * 8, 256, 0, stream>>>(in, outb, ypartB, epack, rowptr,
                                                   perm, w, decay, dmod);
        const unsigned short* tmp = outb;
        outb = (unsigned short*)in;
        in = tmp;
    }

    k_red1<<<24 * 7, 256, 0, stream>>>(ypartA, ypartB, partial);
    k_red2<<<(kL + 255) / 256, 256, 0, stream>>>(partial, env, (float*)d_out);
}